// Round 8
// baseline (620.608 us; speedup 1.0000x reference)
//
#include <hip/hip_runtime.h>
#include <math.h>

#define NB 1024
#define NF 36
#define ED 256
#define NK 8
#define NN2 1296   // 36*36
#define QPK 162    // 1296/8

typedef _Float16 f16;
typedef f16 f16x8 __attribute__((ext_vector_type(8)));
typedef float f32x4 __attribute__((ext_vector_type(4)));

#define NFRAG 1536    // 3 row-tiles * 8 kc * 64 lanes (f16x8 each)
#define WXPSTR 72     // f16 per private-Wx row (64 + 8; 144 B = 9*16, b128-aligned all rows)
#define SSTR 49       // f32 per S row (48 + 1: breaks 4-way ds_add banking)

// ---- ntn_main LDS (dynamic): Xh | 4x wave-private Wx | S(48x49 f32) | v ----
#define XH_OFF  0
#define WXP_OFF 24576                     // 4 * 48*72*2 = 27648
#define S_OFF   52224                     // 48*49*4 = 9408
#define V_OFF   61632                     // v1s 144 + v2s 144 + Uws 36
#define SMEM_MAIN 61956                   // ~60.5 KB -> 2 blocks/CU

// ---- prep_all LDS layout (dynamic, 64 KiB) ----
#define PXH_OFF 0
#define PXL_OFF 24576
#define PVH_OFF 49152
#define PVL_OFF 57344
#define SMEM_PREP 65536

__device__ __forceinline__ f32x4 mfma16(f16x8 a, f16x8 b, f32x4 c) {
    return __builtin_amdgcn_mfma_f32_16x16x32_f16(a, b, c, 0, 0, 0);
}

// Merged prep: blocks [0,256) pack W -> B-frag order, HI ONLY (scaled by 16);
// blocks [256,1280) split X into fragment-order hi/lo and compute v12 via MFMA.
__global__ __launch_bounds__(256) void prep_all(
    const float* __restrict__ W, f16x8* __restrict__ WfH,
    const float* __restrict__ texts, f16x8* __restrict__ XfH, f16x8* __restrict__ XfL,
    const float* __restrict__ V1w, const float* __restrict__ V1b,
    const float* __restrict__ V2w, const float* __restrict__ V2b,
    float* __restrict__ v12)
{
    extern __shared__ char psmem[];
    const int blk = blockIdx.x;
    const int t = threadIdx.x;

    if (blk < 256) {   // ---- W fragment pack (hi only) ----
        int idx = blk * 256 + t;       // 65536 total
        int dox = idx & 31;
        int c   = (idx >> 5) & 255;
        int k   = idx >> 13;
        const float* src = W + ((size_t)(k * 256 + c)) * 256 + dox * 8;
        float4 a = *(const float4*)src;
        float4 b = *(const float4*)(src + 4);
        float v[8] = {a.x, a.y, a.z, a.w, b.x, b.y, b.z, b.w};
        f16x8 hi;
        #pragma unroll
        for (int j = 0; j < 8; ++j) hi[j] = (f16)(v[j] * 16.0f);
        int kc = dox >> 2, qd = dox & 3, ct = c >> 4;
        int fr = ((k * 16 + ct) * 8 + kc) * 64 + qd * 16 + (c & 15);
        WfH[fr] = hi;
        return;
    }

    // ---- X fragment pack + v12 via MFMA ----
    f16x8* XsH = (f16x8*)(psmem + PXH_OFF);
    f16x8* XsL = (f16x8*)(psmem + PXL_OFF);
    f16x8* VfH = (f16x8*)(psmem + PVH_OFF);
    f16x8* VfL = (f16x8*)(psmem + PVL_OFF);

    const int b = blk - 256;
    const float* xb = texts + (size_t)b * NF * ED;

    // V fragments: col = which*8 + k at lane&15; scaled by 16
    #pragma unroll
    for (int i0 = 0; i0 < 2; ++i0) {
        int i = t + i0 * 256;          // [0,512)
        int kc = (i >> 6) & 7, lane = i & 63;
        int q = lane >> 4, col = lane & 15;
        int which = col >> 3, kk = col & 7;
        const float* src = (which ? V2w : V1w) + kk * 256 + kc * 32 + q * 8;
        f16x8 hi, lo;
        #pragma unroll
        for (int j = 0; j < 8; ++j) {
            float sv = src[j] * 16.0f;
            f16 h = (f16)sv;
            hi[j] = h;
            lo[j] = (f16)(sv - (float)h);
        }
        VfH[i] = hi;
        VfL[i] = lo;
    }

    // X fragments: XsH[(rt*8+kc)*64 + q*16+l15] = X[rt*16+l15][kc*32+q*8..+7]
    #pragma unroll
    for (int i0 = 0; i0 < 6; ++i0) {
        int i = t + i0 * 256;          // [0,1536)
        int rt = i >> 9, kc = (i >> 6) & 7, lane = i & 63;
        int q = lane >> 4, l15 = lane & 15;
        int row = rt * 16 + l15;
        f16x8 hi, lo;
        if (row < NF) {
            const float* s = xb + row * ED + kc * 32 + q * 8;
            float4 a = *(const float4*)s;
            float4 c = *(const float4*)(s + 4);
            float v[8] = {a.x, a.y, a.z, a.w, c.x, c.y, c.z, c.w};
            #pragma unroll
            for (int j = 0; j < 8; ++j) {
                f16 h = (f16)v[j];
                hi[j] = h;
                lo[j] = (f16)(v[j] - (float)h);
            }
        } else {
            #pragma unroll
            for (int j = 0; j < 8; ++j) { hi[j] = (f16)0.f; lo[j] = (f16)0.f; }
        }
        XsH[i] = hi;
        XsL[i] = lo;
        XfH[(size_t)b * NFRAG + i] = hi;
        XfL[(size_t)b * NFRAG + i] = lo;
    }
    __syncthreads();

    // v12 MFMA: wave w (<3) handles row-tile rt=w
    const int wave = t >> 6, lane = t & 63;
    const int q = lane >> 4, l15 = lane & 15;
    if (wave < 3) {
        f32x4 acc = (f32x4){0.f, 0.f, 0.f, 0.f};
        #pragma unroll
        for (int kc = 0; kc < 8; ++kc) {
            f16x8 ah = XsH[(wave * 8 + kc) * 64 + lane];
            f16x8 al = XsL[(wave * 8 + kc) * 64 + lane];
            f16x8 bh = VfH[kc * 64 + lane];
            f16x8 bl = VfL[kc * 64 + lane];
            acc = mfma16(ah, bh, acc);
            acc = mfma16(ah, bl, acc);
            acc = mfma16(al, bh, acc);
        }
        const int which = l15 >> 3, kk = l15 & 7;
        const float bias = which ? V2b[kk] : V1b[kk];
        #pragma unroll
        for (int r = 0; r < 4; ++r) {
            const int n = wave * 16 + q * 4 + r;
            if (n < NF)
                v12[((size_t)b * 16 + l15) * NF + n] = acc[r] * 0.0625f + bias;
        }
    }
}

// Barrier-free main loop: each wave owns 4 ct-tiles (64 c-cols). Phase-1
// (Wx = X*W^T, terms AhBh + AlBh) -> wave-private LDS -> phase-2 partial
// S over own c-range -> ds_add_f32 reduce into shared S. Only 2 barriers.
__global__ __launch_bounds__(256, 2) void ntn_main(
    const f16x8* __restrict__ XfHG, const f16x8* __restrict__ XfLG,
    const f16x8* __restrict__ WfH,
    const float* __restrict__ Wb, const float* __restrict__ v12,
    const float* __restrict__ Uw, const float* __restrict__ Ubp,
    float* __restrict__ logits)
{
    extern __shared__ char smem[];
    f16x8* Xh  = (f16x8*)(smem + XH_OFF);
    float* S   = (float*)(smem + S_OFF);     // [48][SSTR]
    float* v1s = (float*)(smem + V_OFF);
    float* v2s = v1s + NF;
    float* Uws = v2s + NF;

    // XCD swizzle: all 8 k's of a b share id%8 (same XCD -> X/W L2-resident)
    const int id  = blockIdx.x;
    const int rem = id >> 3;
    const int k   = rem & 7;
    const int b   = ((rem >> 3) << 3) | (id & 7);

    const int t    = threadIdx.x;
    const int wave = t >> 6;
    const int lane = t & 63;
    const int quad = lane >> 4;
    const int l15  = lane & 15;

    f16* Wxp = (f16*)(smem + WXP_OFF) + wave * (48 * WXPSTR);   // private
    const f16x8* Xlg = XfLG + (size_t)b * NFRAG;

    // ---- stage: X-hi -> LDS, zero S, load v1/v2/U ----
    {
        const f16x8* gh = XfHG + (size_t)b * NFRAG;
        #pragma unroll
        for (int i = 0; i < 6; ++i) Xh[t + i * 256] = gh[t + i * 256];
    }
    {
        float4* Sz = (float4*)S;             // 48*49*4 B = 588 float4
        for (int i = t; i < 588; i += 256) Sz[i] = (float4){0.f, 0.f, 0.f, 0.f};
    }
    if (t < 72) {
        const int which = (t >= NF);
        const int n = t - which * NF;
        float v = v12[((size_t)b * 16 + which * 8 + k) * NF + n];
        if (which) v2s[n] = v; else v1s[n] = v;
    }
    if (t < 8) Uws[t] = Uw[t];
    if (t == 8) Uws[8] = Ubp[0];

    float wbv[4];
    #pragma unroll
    for (int j = 0; j < 4; ++j) wbv[j] = Wb[k * ED + (wave * 4 + j) * 16 + l15];
    __syncthreads();

    const f16x8* WfHk = WfH + (size_t)k * 16 * 8 * 64;

    // ===== phase 1: Wx[:, wave's 64 cols] = X * W[k]^T (AhBh + AlBh) =====
    f32x4 acc[3][4];
    #pragma unroll
    for (int i = 0; i < 3; ++i)
        #pragma unroll
        for (int j = 0; j < 4; ++j) acc[i][j] = (f32x4){0.f, 0.f, 0.f, 0.f};

    #pragma unroll 2
    for (int kc = 0; kc < 8; ++kc) {
        f16x8 ah[3], al[3];
        #pragma unroll
        for (int rt = 0; rt < 3; ++rt) {
            ah[rt] = Xh[(rt * 8 + kc) * 64 + lane];      // LDS
            al[rt] = Xlg[(rt * 8 + kc) * 64 + lane];     // global (L1-shared across waves)
        }
        f16x8 bh[4];
        #pragma unroll
        for (int j = 0; j < 4; ++j)
            bh[j] = WfHk[((wave * 4 + j) * 8 + kc) * 64 + lane];
        #pragma unroll
        for (int rt = 0; rt < 3; ++rt)
            #pragma unroll
            for (int j = 0; j < 4; ++j) {
                acc[rt][j] = mfma16(ah[rt], bh[j], acc[rt][j]);
                acc[rt][j] = mfma16(al[rt], bh[j], acc[rt][j]);
            }
    }

    // ---- unscale + bias, store hi to wave-private LDS (no barrier needed) ----
    #pragma unroll
    for (int rt = 0; rt < 3; ++rt)
        #pragma unroll
        for (int j = 0; j < 4; ++j)
            #pragma unroll
            for (int r = 0; r < 4; ++r) {
                const int row = rt * 16 + quad * 4 + r;
                Wxp[row * WXPSTR + j * 16 + l15] = (f16)(acc[rt][j][r] * 0.0625f + wbv[j]);
            }

    // ===== phase 2: partial S over wave's 64 c-cols (same-wave LDS RAW) =====
    f32x4 sacc[9];
    #pragma unroll
    for (int i = 0; i < 9; ++i) sacc[i] = (f32x4){0.f, 0.f, 0.f, 0.f};

    #pragma unroll
    for (int gl = 0; gl < 2; ++gl) {
        f16x8 pah[3];
        #pragma unroll
        for (int nt = 0; nt < 3; ++nt)
            pah[nt] = *(const f16x8*)(Wxp + (nt * 16 + l15) * WXPSTR + gl * 32 + quad * 8);
        const int kcg = wave * 2 + gl;    // global 32-c group index
        #pragma unroll
        for (int mt = 0; mt < 3; ++mt) {
            f16x8 pbh = Xh[(mt * 8 + kcg) * 64 + lane];
            f16x8 pbl = Xlg[(mt * 8 + kcg) * 64 + lane];
            #pragma unroll
            for (int nt = 0; nt < 3; ++nt) {
                sacc[nt * 3 + mt] = mfma16(pah[nt], pbh, sacc[nt * 3 + mt]);
                sacc[nt * 3 + mt] = mfma16(pah[nt], pbl, sacc[nt * 3 + mt]);
            }
        }
    }

    // ---- reduce partial S across waves (LDS f32 atomics) ----
    #pragma unroll
    for (int nt = 0; nt < 3; ++nt)
        #pragma unroll
        for (int mt = 0; mt < 3; ++mt)
            #pragma unroll
            for (int r = 0; r < 4; ++r)
                atomicAdd(&S[(nt * 16 + quad * 4 + r) * SSTR + mt * 16 + l15],
                          sacc[nt * 3 + mt][r]);
    __syncthreads();

    // ===== epilogue: T = tanh(S + v1 + v2) in place, then U-dot =====
    for (int idx = t; idx < NN2; idx += 256) {
        const int n = idx / NF, m = idx - n * NF;
        float sv = S[n * SSTR + m] + v1s[n] + v2s[m];
        float e = __expf(2.f * sv);
        S[n * SSTR + m] = 1.f - 2.f / (e + 1.f);   // same slot: no race
    }
    __syncthreads();
    if (t < QPK) {
        float lg = Uws[8];
        #pragma unroll
        for (int j = 0; j < 8; ++j) {
            const int flat = t * 8 + j;
            const int n = flat / NF, m = flat - n * NF;
            lg += Uws[j] * S[n * SSTR + m];
        }
        logits[(size_t)b * NN2 + k * QPK + t] = lg;
    }
}

// ---- in-place row softmax: 4 rows per 256-thread block (one per wave) ----
__global__ __launch_bounds__(256) void softmax_rows(float* __restrict__ out) {
    int row = blockIdx.x * 4 + (threadIdx.x >> 6);
    int t = threadIdx.x & 63;
    float* p = out + (size_t)row * NF;
    float v = (t < NF) ? p[t] : -INFINITY;
    float mx = v;
    #pragma unroll
    for (int off = 32; off > 0; off >>= 1) mx = fmaxf(mx, __shfl_xor(mx, off));
    float e = (t < NF) ? __expf(v - mx) : 0.f;
    float sm = e;
    #pragma unroll
    for (int off = 32; off > 0; off >>= 1) sm += __shfl_xor(sm, off);
    if (t < NF) p[t] = e / sm;
}

extern "C" void kernel_launch(void* const* d_in, const int* in_sizes, int n_in,
                              void* d_out, int out_size, void* d_ws, size_t ws_size,
                              hipStream_t stream) {
    const float* texts = (const float*)d_in[0];
    const float* W     = (const float*)d_in[1];
    const float* Wb    = (const float*)d_in[2];
    const float* V1w   = (const float*)d_in[3];
    const float* V1b   = (const float*)d_in[4];
    const float* V2w   = (const float*)d_in[5];
    const float* V2b   = (const float*)d_in[6];
    const float* Uw    = (const float*)d_in[7];
    const float* Ub    = (const float*)d_in[8];

    char* ws = (char*)d_ws;
    f16x8* WfH = (f16x8*)ws;                                   //  1 MiB
    f16x8* XfH = (f16x8*)(ws + (1 << 20));                     // 24 MiB
    f16x8* XfL = (f16x8*)(ws + (1 << 20) + (size_t)NB * NFRAG * 16);       // 24 MiB
    float* v12 = (float*)(ws + (1 << 20) + (size_t)2 * NB * NFRAG * 16);   // 2.25 MiB
    float* logits = (float*)d_out;

    hipFuncSetAttribute((const void*)prep_all,
                        hipFuncAttributeMaxDynamicSharedMemorySize, SMEM_PREP);
    hipFuncSetAttribute((const void*)ntn_main,
                        hipFuncAttributeMaxDynamicSharedMemorySize, SMEM_MAIN);

    prep_all<<<256 + NB, 256, SMEM_PREP, stream>>>(W, WfH, texts, XfH, XfL,
                                                   V1w, V1b, V2w, V2b, v12);
    ntn_main<<<NB * NK, 256, SMEM_MAIN, stream>>>(XfH, XfL, WfH, Wb, v12, Uw, Ub, logits);
    softmax_rows<<<NB * NF / 4, 256, 0, stream>>>(logits);
}

// Round 9
// 247.092 us; speedup vs baseline: 2.5117x; 2.5117x over previous
//
#include <hip/hip_runtime.h>
#include <math.h>

#define NB 1024
#define NF 36
#define ED 256
#define NK 8
#define NN2 1296   // 36*36
#define QPK 162    // 1296/8

typedef _Float16 f16;
typedef f16 f16x8 __attribute__((ext_vector_type(8)));
typedef float f32x4 __attribute__((ext_vector_type(4)));

#define WXSTR 136     // f16 per Wx half-row (128 + 8 pad); 272B = 17*16 (b128-aligned)
#define NFRAG 1536    // 3 row-tiles * 8 kc * 64 lanes, f16x8 each

// ---- ntn_main LDS (dynamic): Xh | Wxh | v  ~= 37 KB -> 4 blocks/CU ----
#define XH_OFF  0
#define WXH_OFF 24576                 // 48 * WXSTR * 2 = 13056
#define V_OFF   37632
#define SMEM_MAIN (V_OFF + (NF + NF + 9) * 4)   // 37956

// ---- prep_all LDS layout (dynamic, 64 KiB) ----
#define PXH_OFF 0
#define PXL_OFF 24576
#define PVH_OFF 49152
#define PVL_OFF 57344
#define SMEM_PREP 65536

__device__ __forceinline__ f32x4 mfma16(f16x8 a, f16x8 b, f32x4 c) {
    return __builtin_amdgcn_mfma_f32_16x16x32_f16(a, b, c, 0, 0, 0);
}

// Merged prep: blocks [0,256) pack W -> B-frag order HI ONLY (scaled by 16);
// blocks [256,1280) split X into fragment-order hi/lo and compute v12 via MFMA.
__global__ __launch_bounds__(256) void prep_all(
    const float* __restrict__ W, f16x8* __restrict__ WfH,
    const float* __restrict__ texts, f16x8* __restrict__ XfH, f16x8* __restrict__ XfL,
    const float* __restrict__ V1w, const float* __restrict__ V1b,
    const float* __restrict__ V2w, const float* __restrict__ V2b,
    float* __restrict__ v12)
{
    extern __shared__ char psmem[];
    const int blk = blockIdx.x;
    const int t = threadIdx.x;

    if (blk < 256) {   // ---- W fragment pack (hi only) ----
        int idx = blk * 256 + t;       // 65536 total
        int dox = idx & 31;
        int c   = (idx >> 5) & 255;
        int k   = idx >> 13;
        const float* src = W + ((size_t)(k * 256 + c)) * 256 + dox * 8;
        float4 a = *(const float4*)src;
        float4 b = *(const float4*)(src + 4);
        float v[8] = {a.x, a.y, a.z, a.w, b.x, b.y, b.z, b.w};
        f16x8 hi;
        #pragma unroll
        for (int j = 0; j < 8; ++j) hi[j] = (f16)(v[j] * 16.0f);
        int kc = dox >> 2, qd = dox & 3, ct = c >> 4;
        int fr = ((k * 16 + ct) * 8 + kc) * 64 + qd * 16 + (c & 15);
        WfH[fr] = hi;
        return;
    }

    // ---- X fragment pack + v12 via MFMA ----
    f16x8* XsH = (f16x8*)(psmem + PXH_OFF);
    f16x8* XsL = (f16x8*)(psmem + PXL_OFF);
    f16x8* VfH = (f16x8*)(psmem + PVH_OFF);
    f16x8* VfL = (f16x8*)(psmem + PVL_OFF);

    const int b = blk - 256;
    const float* xb = texts + (size_t)b * NF * ED;

    // V fragments: col = which*8 + k at lane&15; scaled by 16
    #pragma unroll
    for (int i0 = 0; i0 < 2; ++i0) {
        int i = t + i0 * 256;          // [0,512)
        int kc = (i >> 6) & 7, lane = i & 63;
        int q = lane >> 4, col = lane & 15;
        int which = col >> 3, kk = col & 7;
        const float* src = (which ? V2w : V1w) + kk * 256 + kc * 32 + q * 8;
        f16x8 hi, lo;
        #pragma unroll
        for (int j = 0; j < 8; ++j) {
            float sv = src[j] * 16.0f;
            f16 h = (f16)sv;
            hi[j] = h;
            lo[j] = (f16)(sv - (float)h);
        }
        VfH[i] = hi;
        VfL[i] = lo;
    }

    // X fragments: XsH[(rt*8+kc)*64 + q*16+l15] = X[rt*16+l15][kc*32+q*8..+7]
    #pragma unroll
    for (int i0 = 0; i0 < 6; ++i0) {
        int i = t + i0 * 256;          // [0,1536)
        int rt = i >> 9, kc = (i >> 6) & 7, lane = i & 63;
        int q = lane >> 4, l15 = lane & 15;
        int row = rt * 16 + l15;
        f16x8 hi, lo;
        if (row < NF) {
            const float* s = xb + row * ED + kc * 32 + q * 8;
            float4 a = *(const float4*)s;
            float4 c = *(const float4*)(s + 4);
            float v[8] = {a.x, a.y, a.z, a.w, c.x, c.y, c.z, c.w};
            #pragma unroll
            for (int j = 0; j < 8; ++j) {
                f16 h = (f16)v[j];
                hi[j] = h;
                lo[j] = (f16)(v[j] - (float)h);
            }
        } else {
            #pragma unroll
            for (int j = 0; j < 8; ++j) { hi[j] = (f16)0.f; lo[j] = (f16)0.f; }
        }
        XsH[i] = hi;
        XsL[i] = lo;
        XfH[(size_t)b * NFRAG + i] = hi;
        XfL[(size_t)b * NFRAG + i] = lo;
    }
    __syncthreads();

    // v12 MFMA: wave w (<3) handles row-tile rt=w
    const int wave = t >> 6, lane = t & 63;
    const int q = lane >> 4, l15 = lane & 15;
    if (wave < 3) {
        f32x4 acc = (f32x4){0.f, 0.f, 0.f, 0.f};
        #pragma unroll
        for (int kc = 0; kc < 8; ++kc) {
            f16x8 ah = XsH[(wave * 8 + kc) * 64 + lane];
            f16x8 al = XsL[(wave * 8 + kc) * 64 + lane];
            f16x8 bh = VfH[kc * 64 + lane];
            f16x8 bl = VfL[kc * 64 + lane];
            acc = mfma16(ah, bh, acc);
            acc = mfma16(ah, bl, acc);
            acc = mfma16(al, bh, acc);
        }
        const int which = l15 >> 3, kk = l15 & 7;
        const float bias = which ? V2b[kk] : V1b[kk];
        #pragma unroll
        for (int r = 0; r < 4; ++r) {
            const int n = wave * 16 + q * 4 + r;
            if (n < NF)
                v12[((size_t)b * 16 + l15) * NF + n] = acc[r] * 0.0625f + bias;
        }
    }
}

// R6 skeleton + validated 2-term numerics (no W-lo, no Wx-lo).
__global__ __launch_bounds__(256, 4) void ntn_main(
    const f16x8* __restrict__ XfHG, const f16x8* __restrict__ XfLG,
    const f16x8* __restrict__ WfH,
    const float* __restrict__ Wb, const float* __restrict__ v12,
    const float* __restrict__ Uw, const float* __restrict__ Ubp,
    float* __restrict__ logits)
{
    extern __shared__ char smem[];
    f16x8* Xh  = (f16x8*)(smem + XH_OFF);
    f16*   Wxh = (f16*)(smem + WXH_OFF);
    float* v1s = (float*)(smem + V_OFF);
    float* v2s = v1s + NF;
    float* Uws = v2s + NF;

    // XCD swizzle: all 8 k's of a b share id%8 (same XCD -> X/W L2-resident)
    const int id  = blockIdx.x;
    const int rem = id >> 3;
    const int k   = rem & 7;
    const int b   = ((rem >> 3) << 3) | (id & 7);

    const int t    = threadIdx.x;
    const int wave = t >> 6;
    const int lane = t & 63;
    const int quad = lane >> 4;
    const int l15  = lane & 15;

    const f16x8* Xlg = XfLG + (size_t)b * NFRAG;   // X-lo: global (L2/L1-broadcast)

    // ---- stage X-hi fragments into LDS (coalesced dwordx4) ----
    {
        const f16x8* gh = XfHG + (size_t)b * NFRAG;
        #pragma unroll
        for (int i = 0; i < 6; ++i) Xh[t + i * 256] = gh[t + i * 256];
    }
    if (t < 72) {
        const int which = (t >= NF);
        const int n = t - which * NF;
        float v = v12[((size_t)b * 16 + which * 8 + k) * NF + n];
        if (which) v2s[n] = v; else v1s[n] = v;
    }
    if (t < 8) Uws[t] = Uw[t];
    if (t == 8) Uws[8] = Ubp[0];

    float wbv[2][2];
    #pragma unroll
    for (int h = 0; h < 2; ++h) {
        wbv[h][0] = Wb[k * ED + (h * 8 + wave) * 16 + l15];
        wbv[h][1] = Wb[k * ED + (h * 8 + wave + 4) * 16 + l15];
    }
    __syncthreads();

    const f16x8* WfHk = WfH + (size_t)k * 16 * 8 * 64;

    f32x4 sacc[3];
    #pragma unroll
    for (int i = 0; i < 3; ++i) sacc[i] = (f32x4){0.f, 0.f, 0.f, 0.f};

    for (int h = 0; h < 2; ++h) {
        // ===== phase 1: Wx[:, half h] = X * W[k]^T (AhBh + AlBh, W-hi only) =====
        f32x4 acc[3][2];
        #pragma unroll
        for (int i = 0; i < 3; ++i) { acc[i][0] = (f32x4){0,0,0,0}; acc[i][1] = (f32x4){0,0,0,0}; }
        const int ct0 = h * 8 + wave;
        const int ct1 = ct0 + 4;
        #pragma unroll 2
        for (int kc = 0; kc < 8; ++kc) {
            f16x8 ah[3], al[3];
            #pragma unroll
            for (int rt = 0; rt < 3; ++rt) {
                ah[rt] = Xh[(rt * 8 + kc) * 64 + lane];    // LDS ds_read_b128
                al[rt] = Xlg[(rt * 8 + kc) * 64 + lane];   // global (L2/L1)
            }
            f16x8 bh0 = WfHk[(ct0 * 8 + kc) * 64 + lane];
            f16x8 bh1 = WfHk[(ct1 * 8 + kc) * 64 + lane];
            #pragma unroll
            for (int rt = 0; rt < 3; ++rt) {
                acc[rt][0] = mfma16(ah[rt], bh0, acc[rt][0]);
                acc[rt][0] = mfma16(al[rt], bh0, acc[rt][0]);
                acc[rt][1] = mfma16(ah[rt], bh1, acc[rt][1]);
                acc[rt][1] = mfma16(al[rt], bh1, acc[rt][1]);
            }
        }
        __syncthreads();   // prior phase-2 readers of Wxh are done
        // ---- unscale (W was *16), add bias, store hi-only -> LDS ----
        #pragma unroll
        for (int rt = 0; rt < 3; ++rt) {
            #pragma unroll
            for (int j2 = 0; j2 < 2; ++j2) {
                const float wb = wbv[h][j2];
                const int cl = (j2 ? (wave + 4) : wave) * 16 + l15;
                #pragma unroll
                for (int r = 0; r < 4; ++r) {
                    const int row = rt * 16 + quad * 4 + r;
                    Wxh[row * WXSTR + cl] = (f16)(acc[rt][j2][r] * 0.0625f + wb);
                }
            }
        }
        __syncthreads();
        // ===== phase 2: S += Wxh * (Xh + Xl)^T (9 tiles over 4 waves) =====
        #pragma unroll
        for (int it = 0; it < 3; ++it) {
            const int p = wave + it * 4;
            if (p < 9) {
                const int nt = p / 3, mt = p % 3;
                const f16* wxh_p = Wxh + (nt * 16 + l15) * WXSTR + quad * 8;
                #pragma unroll
                for (int kc2 = 0; kc2 < 4; ++kc2) {
                    f16x8 pah = *(const f16x8*)(wxh_p + kc2 * 32);
                    f16x8 pbh = Xh[(mt * 8 + h * 4 + kc2) * 64 + lane];
                    f16x8 pbl = Xlg[(mt * 8 + h * 4 + kc2) * 64 + lane];
                    sacc[it] = mfma16(pah, pbh, sacc[it]);
                    sacc[it] = mfma16(pah, pbl, sacc[it]);
                }
            }
        }
    }

    // ===== epilogue: T = tanh(S + v1 + v2) -> Ts (overlays Wxh), U-dot =====
    __syncthreads();
    float* Ts = (float*)Wxh;   // 1296 f32 = 5184 B <= 13056 B
    #pragma unroll
    for (int it = 0; it < 3; ++it) {
        const int p = wave + it * 4;
        if (p < 9) {
            const int nt = p / 3, mt = p % 3;
            const int m = mt * 16 + l15;
            if (m < NF) {
                #pragma unroll
                for (int r = 0; r < 4; ++r) {
                    const int n = nt * 16 + quad * 4 + r;
                    if (n < NF) {
                        float sv = sacc[it][r] + v1s[n] + v2s[m];
                        float e = __expf(2.f * sv);
                        Ts[n * NF + m] = 1.f - 2.f / (e + 1.f);
                    }
                }
            }
        }
    }
    __syncthreads();
    if (t < QPK) {
        const float* tp = Ts + t * 8;
        float lg = Uws[8];
        #pragma unroll
        for (int j = 0; j < 8; ++j) lg += Uws[j] * tp[j];
        logits[(size_t)b * NN2 + k * QPK + t] = lg;
    }
}

// ---- in-place row softmax: 4 rows per 256-thread block (one per wave) ----
__global__ __launch_bounds__(256) void softmax_rows(float* __restrict__ out) {
    int row = blockIdx.x * 4 + (threadIdx.x >> 6);
    int t = threadIdx.x & 63;
    float* p = out + (size_t)row * NF;
    float v = (t < NF) ? p[t] : -INFINITY;
    float mx = v;
    #pragma unroll
    for (int off = 32; off > 0; off >>= 1) mx = fmaxf(mx, __shfl_xor(mx, off));
    float e = (t < NF) ? __expf(v - mx) : 0.f;
    float sm = e;
    #pragma unroll
    for (int off = 32; off > 0; off >>= 1) sm += __shfl_xor(sm, off);
    if (t < NF) p[t] = e / sm;
}

extern "C" void kernel_launch(void* const* d_in, const int* in_sizes, int n_in,
                              void* d_out, int out_size, void* d_ws, size_t ws_size,
                              hipStream_t stream) {
    const float* texts = (const float*)d_in[0];
    const float* W     = (const float*)d_in[1];
    const float* Wb    = (const float*)d_in[2];
    const float* V1w   = (const float*)d_in[3];
    const float* V1b   = (const float*)d_in[4];
    const float* V2w   = (const float*)d_in[5];
    const float* V2b   = (const float*)d_in[6];
    const float* Uw    = (const float*)d_in[7];
    const float* Ub    = (const float*)d_in[8];

    char* ws = (char*)d_ws;
    f16x8* WfH = (f16x8*)ws;                                   //  1 MiB
    f16x8* XfH = (f16x8*)(ws + (1 << 20));                     // 24 MiB
    f16x8* XfL = (f16x8*)(ws + (1 << 20) + (size_t)NB * NFRAG * 16);       // 24 MiB
    float* v12 = (float*)(ws + (1 << 20) + (size_t)2 * NB * NFRAG * 16);   // 2.25 MiB
    float* logits = (float*)d_out;

    hipFuncSetAttribute((const void*)prep_all,
                        hipFuncAttributeMaxDynamicSharedMemorySize, SMEM_PREP);
    hipFuncSetAttribute((const void*)ntn_main,
                        hipFuncAttributeMaxDynamicSharedMemorySize, SMEM_MAIN);

    prep_all<<<256 + NB, 256, SMEM_PREP, stream>>>(W, WfH, texts, XfH, XfL,
                                                   V1w, V1b, V2w, V2b, v12);
    ntn_main<<<NB * NK, 256, SMEM_MAIN, stream>>>(XfH, XfL, WfH, Wb, v12, Uw, Ub, logits);
    softmax_rows<<<NB * NF / 4, 256, 0, stream>>>(logits);
}